// Round 21
// baseline (37.807 us; speedup 1.0000x reference)
//
#include <hip/hip_runtime.h>
#include <math.h>

#define ALPHA 0.2f
#define MAXK 10

typedef _Float16 half8 __attribute__((ext_vector_type(8)));
typedef _Float16 half4 __attribute__((ext_vector_type(4)));
typedef float f32x4 __attribute__((ext_vector_type(4)));

__device__ __forceinline__ void gload_lds16(const void* g, void* l) {
    __builtin_amdgcn_global_load_lds(
        (const __attribute__((address_space(1))) unsigned int*)g,
        (__attribute__((address_space(3))) unsigned int*)l, 16, 0, 0);
}

__device__ __forceinline__ float dot4(float4 a, float4 b) {
    return a.x * b.x + a.y * b.y + a.z * b.z + a.w * b.w;
}

// D1: blocks [0, F/4): wa = W @ [a1,a2] (one wave per W row);
// blocks [F/4, F/4 + (F/32)^2): W->Wt fp16 transpose. (R17-proven, 36.70us)
__global__ __launch_bounds__(256) void prep_kernel(
    const float* __restrict__ W, const float* __restrict__ a,
    float* __restrict__ wa, _Float16* __restrict__ Wt, int F) {
    const int tid = threadIdx.x;
    const int nWa = F >> 2;                      // 256 blocks: 4 waves each

    if ((int)blockIdx.x >= nWa) {
        // ---- transpose: Wt[n][k] = (fp16) W[k][n], 32x32 tiles ----
        __shared__ float t[32][33];
        const int tb = blockIdx.x - nWa;
        const int tpr = F >> 5;
        const int bx = (tb % tpr) * 32;
        const int by = (tb / tpr) * 32;
        const int x = tid & 31, y = tid >> 5;
        for (int i2 = y; i2 < 32; i2 += 8)
            t[i2][x] = W[(size_t)(bx + i2) * F + by + x];
        __syncthreads();
        for (int i2 = y; i2 < 32; i2 += 8)
            Wt[(size_t)(by + i2) * F + bx + x] = (_Float16)t[x][i2];
        return;
    }

    // ---- wa: one wave per W row ----
    int wave = (int)((blockIdx.x * blockDim.x + tid) >> 6);
    int lane = tid & 63;
    const float4* wr = reinterpret_cast<const float4*>(W + (size_t)wave * F);
    const float4* a1 = reinterpret_cast<const float4*>(a);
    const float4* a2 = reinterpret_cast<const float4*>(a + F);
    float acc1 = 0.f, acc2 = 0.f;
    int F4 = F >> 2;
    for (int c = lane; c < F4; c += 64) {
        float4 w = wr[c];
        acc1 += dot4(w, a1[c]);
        acc2 += dot4(w, a2[c]);
    }
    #pragma unroll
    for (int off = 32; off; off >>= 1) {
        acc1 += __shfl_down(acc1, off);
        acc2 += __shfl_down(acc2, off);
    }
    if (lane == 0) { wa[wave] = acc1; wa[F + wave] = acc2; }
}

// D2: aggregate (R9/R17-proven body), one block per output row. Register-
// resident row cache: each gathered row read exactly once (R10 showed
// re-reading costs +10us; R16 showed LDS-stash is neutral; R19/R20 showed
// byte- and request-halving are neutral -> gather-tier floor).
__global__ __launch_bounds__(256) void mid_kernel(
    const float* __restrict__ feat, const float* __restrict__ embed,
    const int* __restrict__ nidx, const float* __restrict__ wa,
    _Float16* __restrict__ agg, int F) {
    const int tid = threadIdx.x;
    const int i = blockIdx.x;
    const int f = tid * 4;

    int idx[MAXK];
    bool dup[MAXK];
    #pragma unroll
    for (int k = 0; k < MAXK; k++) idx[k] = nidx[i * MAXK + k];
    #pragma unroll
    for (int k = 0; k < MAXK; k++) {
        bool d = false;
        #pragma unroll
        for (int p = 0; p < MAXK; p++)
            if (p < k) d |= (idx[p] == idx[k]);
        dup[k] = d;
    }

    float4 wa1 = *(const float4*)&wa[f];
    float4 wa2 = *(const float4*)&wa[F + f];
    float4 fv  = *(const float4*)&feat[(size_t)i * F + f];
    float a1p = dot4(fv, wa1);

    float4 rv[MAXK];
    float a2p[MAXK];
    #pragma unroll
    for (int k = 0; k < MAXK; k++) {
        rv[k] = *(const float4*)&embed[(size_t)idx[k] * F + f];
        a2p[k] = dot4(rv[k], wa2);
    }

    #pragma unroll
    for (int off = 32; off; off >>= 1) {
        a1p += __shfl_down(a1p, off);
        #pragma unroll
        for (int k = 0; k < MAXK; k++) a2p[k] += __shfl_down(a2p[k], off);
    }
    __shared__ float red[MAXK + 1][4];
    const int w = tid >> 6, l = tid & 63;
    if (l == 0) {
        red[0][w] = a1p;
        #pragma unroll
        for (int k = 0; k < MAXK; k++) red[k + 1][w] = a2p[k];
    }
    __syncthreads();

    float s1 = red[0][0] + red[0][1] + red[0][2] + red[0][3];
    float sc[MAXK];
    float m = -INFINITY;
    #pragma unroll
    for (int k = 0; k < MAXK; k++) {
        float v = s1 + red[k + 1][0] + red[k + 1][1] + red[k + 1][2] + red[k + 1][3];
        v = v > 0.f ? v : ALPHA * v;
        sc[k] = v;
        if (!dup[k]) m = fmaxf(m, v);
    }
    float sum = 0.f;
    #pragma unroll
    for (int k = 0; k < MAXK; k++) {
        sc[k] = dup[k] ? 0.f : expf(sc[k] - m);
        sum += sc[k];
    }
    float inv = 1.0f / sum;

    float4 o = make_float4(0.f, 0.f, 0.f, 0.f);
    #pragma unroll
    for (int k = 0; k < MAXK; k++) {
        float wk = sc[k] * inv;
        o.x += wk * rv[k].x;
        o.y += wk * rv[k].y;
        o.z += wk * rv[k].z;
        o.w += wk * rv[k].w;
    }
    half4 h = { (_Float16)o.x, (_Float16)o.y, (_Float16)o.z, (_Float16)o.w };
    *(half4*)&agg[(size_t)i * F + f] = h;
}

// D3: C = A @ Bt^T — EXACT R9/R17 config (best known): 64x64 tile, BK=128,
// 4 waves, 2-buffer LDS, counted vmcnt(8) + raw s_barrier, rule-21 swizzle,
// setprio, bijective XCD swizzle. Measured ~8.7us (R13 duplication test),
// ~494 TF on this 2048x1024x1024 shape.
__global__ __launch_bounds__(256) void gemm_f16_kernel(
    const _Float16* __restrict__ A, const _Float16* __restrict__ Bt,
    float* __restrict__ C, int M, int N, int K) {
    __shared__ _Float16 As[2][64 * 128];
    __shared__ _Float16 Bs[2][64 * 128];
    const int tid = threadIdx.x;

    int bid = blockIdx.y * gridDim.x + blockIdx.x;
    int nwg = gridDim.x * gridDim.y;
    int cpx = nwg >> 3;                       // nwg % 8 == 0
    int wg = (bid & 7) * cpx + (bid >> 3);
    const int m0 = (wg / gridDim.x) * 64;
    const int n0 = (wg % gridDim.x) * 64;

    const int l = tid & 63, wv = tid >> 6;
    const int wm = wv >> 1, wn = wv & 1;
    const int lrow = l & 15, kc = l >> 4;
    const int nt = K >> 7;                    // 8

    f32x4 acc[2][2] = {};

    #define STAGE(bf, t)                                                            \
    do {                                                                            \
        int k0_ = (t) * 128;                                                        \
        _Pragma("unroll")                                                           \
        for (int j_ = 0; j_ < 4; j_++) {                                            \
            int u_ = wv * 256 + j_ * 64 + l;                                        \
            int row_ = u_ >> 4, slot_ = (u_ & 15) ^ (row_ & 7);                     \
            gload_lds16(&A[(size_t)(m0 + row_) * K + k0_ + slot_ * 8],              \
                        (void*)((char*)&As[bf][0] + u_ * 16));                      \
        }                                                                           \
        _Pragma("unroll")                                                           \
        for (int j_ = 0; j_ < 4; j_++) {                                            \
            int u_ = wv * 256 + j_ * 64 + l;                                        \
            int row_ = u_ >> 4, slot_ = (u_ & 15) ^ (row_ & 7);                     \
            gload_lds16(&Bt[(size_t)(n0 + row_) * K + k0_ + slot_ * 8],             \
                        (void*)((char*)&Bs[bf][0] + u_ * 16));                      \
        }                                                                           \
    } while (0)

    STAGE(0, 0);

    int buf = 0;
    for (int t = 0; t < nt; ++t) {
        if (t + 1 < nt) {
            STAGE(buf ^ 1, t + 1);
            asm volatile("s_waitcnt vmcnt(8)" ::: "memory");   // stage-t landed
        } else {
            asm volatile("s_waitcnt vmcnt(0)" ::: "memory");
        }
        __builtin_amdgcn_s_barrier();          // raw: no vmcnt(0) drain
        __builtin_amdgcn_sched_barrier(0);

        __builtin_amdgcn_s_setprio(1);
        #pragma unroll
        for (int ks = 0; ks < 4; ks++) {       // 4 x K=32 chunks (BK=128)
            half8 av[2], bv[2];
            #pragma unroll
            for (int fq = 0; fq < 2; fq++) {
                int arow = wm * 32 + fq * 16 + lrow;
                int ag = (ks * 4 + kc) ^ (arow & 7);
                av[fq] = *(const half8*)((const char*)&As[buf][0] + arow * 256 + ag * 16);
                int brow = wn * 32 + fq * 16 + lrow;
                int bg = (ks * 4 + kc) ^ (brow & 7);
                bv[fq] = *(const half8*)((const char*)&Bs[buf][0] + brow * 256 + bg * 16);
            }
            #pragma unroll
            for (int fq = 0; fq < 2; fq++)
                #pragma unroll
                for (int g = 0; g < 2; g++)
                    acc[fq][g] = __builtin_amdgcn_mfma_f32_16x16x32_f16(
                        av[fq], bv[g], acc[fq][g], 0, 0, 0);
        }
        __builtin_amdgcn_s_setprio(0);

        __builtin_amdgcn_sched_barrier(0);     // keep consumes before close
        __builtin_amdgcn_s_barrier();
        buf ^= 1;
    }
    #undef STAGE

    // C/D layout: col = lane&15 (=lrow), row = (lane>>4)*4 + r (=kc*4+r)
    #pragma unroll
    for (int fq = 0; fq < 2; fq++)
        #pragma unroll
        for (int g = 0; g < 2; g++)
            #pragma unroll
            for (int r = 0; r < 4; r++)
                C[(size_t)(m0 + wm * 32 + fq * 16 + kc * 4 + r) * N
                  + n0 + wn * 32 + g * 16 + lrow] = acc[fq][g][r];
}

extern "C" void kernel_launch(void* const* d_in, const int* in_sizes, int n_in,
                              void* d_out, int out_size, void* d_ws, size_t ws_size,
                              hipStream_t stream) {
    const float* feat  = (const float*)d_in[0];
    const float* embed = (const float*)d_in[1];
    const float* W     = (const float*)d_in[2];
    const float* a     = (const float*)d_in[3];
    const int*   nidx  = (const int*)d_in[4];

    int F = in_sizes[3] / 2;          // 1024
    int N = in_sizes[0] / F;          // 2048
    int M = in_sizes[1] / F;          // 8192

    float* ws = (float*)d_ws;
    float* wa = ws;                                 // 2F floats
    _Float16* agg_f16 = (_Float16*)(wa + 2 * F);    // N*F halfs
    _Float16* wt_f16  = agg_f16 + (size_t)N * F;    // F*F halfs
    (void)M;

    // D1: wa (blocks [0,256)) + W->Wt transpose (blocks [256, 1280))
    {
        int nWa = F / 4;
        int nT  = (F / 32) * (F / 32);
        prep_kernel<<<nWa + nT, 256, 0, stream>>>(W, a, wa, wt_f16, F);
    }
    // D2: aggregate only
    mid_kernel<<<N, 256, 0, stream>>>(feat, embed, nidx, wa, agg_f16, F);
    // D3: out = agg @ W via MFMA (A=[N][F] fp16, Bt=[F][F] fp16 = W^T)
    {
        dim3 grid(F / 64, N / 64);   // (16, 32) = 512 blocks
        gemm_f16_kernel<<<grid, 256, 0, stream>>>(agg_f16, wt_f16, (float*)d_out, N, F, F);
    }
}